// Round 6
// baseline (1175.071 us; speedup 1.0000x reference)
//
#include <hip/hip_runtime.h>
#include <math.h>

#define EPSF 1e-8f

constexpr int D_    = 128;
constexpr int NTOK  = 131072;   // 1024 * 128
constexpr int NLVL  = 4;
constexpr int NCODE = 256;
constexpr int TPL   = 3;        // tokens per lane-pair
constexpr int TOKB  = 96;       // tokens per block = 32 pairs * TPL
constexpr int CHUNK = 32;       // codes staged in LDS per stage
constexpr int NBLK  = (NTOK + TOKB - 1) / TOKB;   // 1366 (last block: 32 real tokens)
constexpr int SSTR  = 132;      // transpose-stage stride (floats)

// --- Kernel 1: normalize codebook rows: e_n = e / (||e|| + eps) -------------
__global__ __launch_bounds__(64) void normalize_cb(const float* __restrict__ cb,
                                                   float* __restrict__ out) {
  int row = blockIdx.x;           // 0..1023  (level*256 + code)
  int t   = threadIdx.x;          // 0..63
  float a = cb[row * D_ + t];
  float b = cb[row * D_ + t + 64];
  float ss = a * a + b * b;
#pragma unroll
  for (int m = 32; m >= 1; m >>= 1) ss += __shfl_xor(ss, m);
  float denom = sqrtf(ss) + EPSF;
  out[row * D_ + t]      = a / denom;
  out[row * D_ + t + 64] = b / denom;
}

// --- Kernel 2: main RVQ ------------------------------------------------------
// 1 wave per block. Lane = (pair p = lane&31, half h = lane>>5).
// Each pair owns 3 tokens: tok_j = blk*96 + j*32 + p; lane holds dims
// [64h, 64h+64) of each in registers (r0/r1/r2[64], statically indexed).
// Codebook chunk (32 codes) staged in LDS; per code: 16 ds_read_b128 feed
// 192 fmaf (3 tokens) -> LDS traffic/FMA 3x lower than previous round.
// argmax of unnormalized r.e_n == reference argmax of cosine sim, and the
// winning max value IS the projection scalar s.
__global__ __launch_bounds__(64, 2) void rvq_main(const float* __restrict__ x,
                                                  const float* __restrict__ en,
                                                  float* __restrict__ out_xq,
                                                  float* __restrict__ out_idx,
                                                  float* __restrict__ out_s,
                                                  double* __restrict__ lossacc_g) {
  __shared__ float sh[CHUNK * SSTR];   // 16.9 KB: e-chunk (linear 32x128) / transpose buf

  const int t    = threadIdx.x;        // 0..63
  const int p    = t & 31;
  const int h    = t >> 5;
  const size_t base = (size_t)blockIdx.x * TOKB;

  float r0[64], r1[64], r2[64];

  // ---- stage-in: 3 chunks of 32 tokens, coalesced -> LDS -> registers ------
#pragma unroll
  for (int j = 0; j < TPL; ++j) {
    __syncthreads();
    const size_t tb = base + (size_t)j * 32;
#pragma unroll
    for (int it = 0; it < 16; ++it) {
      int g = it * 64 + t;                 // 0..1023 float4 slots (32 tok x 32)
      size_t tok = tb + (size_t)(g >> 5);
      float4 v = make_float4(0.f, 0.f, 0.f, 0.f);
      if (tok < NTOK) v = *(const float4*)(x + tok * D_ + (size_t)(g & 31) * 4);
      *(float4*)&sh[(g >> 5) * SSTR + ((g & 31) << 2)] = v;
    }
    __syncthreads();
    float* rj = nullptr;  // resolved statically below
    if (j == 0) rj = r0; else if (j == 1) rj = r1; else rj = r2;
#pragma unroll
    for (int d4 = 0; d4 < 16; ++d4) {
      float4 v = *(const float4*)&sh[p * SSTR + h * 64 + d4 * 4];
      rj[d4 * 4 + 0] = v.x; rj[d4 * 4 + 1] = v.y;
      rj[d4 * 4 + 2] = v.z; rj[d4 * 4 + 3] = v.w;
    }
  }

  // ---- 4 residual levels ----
  for (int lvl = 0; lvl < NLVL; ++lvl) {
    float bestA = -3.0e38f, bestB = -3.0e38f, bestC = -3.0e38f;
    int   idxA = 0, idxB = 0, idxC = 0;

    for (int ch = 0; ch < NCODE / CHUNK; ++ch) {
      __syncthreads();
      const float4* __restrict__ eg =
          (const float4*)(en + ((size_t)lvl * NCODE + ch * CHUNK) * D_);
#pragma unroll
      for (int it = 0; it < 16; ++it)                   // 32 codes x 128 d = 1024 f4
        ((float4*)sh)[it * 64 + t] = eg[it * 64 + t];
      __syncthreads();

      for (int code = 0; code < CHUNK; ++code) {
        const float* __restrict__ er = &sh[code * D_ + h * 64];
        float a0 = 0.f, a1 = 0.f, a2 = 0.f, a3 = 0.f;
        float b0 = 0.f, b1 = 0.f, b2 = 0.f, b3 = 0.f;
        float c0 = 0.f, c1 = 0.f, c2 = 0.f, c3 = 0.f;
#pragma unroll
        for (int d4 = 0; d4 < 16; ++d4) {
          float4 ev = *(const float4*)&er[d4 * 4];
          a0 = fmaf(ev.x, r0[d4 * 4 + 0], a0);
          a1 = fmaf(ev.y, r0[d4 * 4 + 1], a1);
          a2 = fmaf(ev.z, r0[d4 * 4 + 2], a2);
          a3 = fmaf(ev.w, r0[d4 * 4 + 3], a3);
          b0 = fmaf(ev.x, r1[d4 * 4 + 0], b0);
          b1 = fmaf(ev.y, r1[d4 * 4 + 1], b1);
          b2 = fmaf(ev.z, r1[d4 * 4 + 2], b2);
          b3 = fmaf(ev.w, r1[d4 * 4 + 3], b3);
          c0 = fmaf(ev.x, r2[d4 * 4 + 0], c0);
          c1 = fmaf(ev.y, r2[d4 * 4 + 1], c1);
          c2 = fmaf(ev.z, r2[d4 * 4 + 2], c2);
          c3 = fmaf(ev.w, r2[d4 * 4 + 3], c3);
        }
        float sA = (a0 + a1) + (a2 + a3); sA += __shfl_xor(sA, 32);
        float sB = (b0 + b1) + (b2 + b3); sB += __shfl_xor(sB, 32);
        float sC = (c0 + c1) + (c2 + c3); sC += __shfl_xor(sC, 32);
        int gc = ch * CHUNK + code;
        if (sA > bestA) { bestA = sA; idxA = gc; }   // strict > = first-max tie-break
        if (sB > bestB) { bestB = sB; idxB = gc; }
        if (sC > bestC) { bestC = sC; idxC = gc; }
      }
    }

    // ---- update: gather winner rows from L2; r -= s*e; loss ----------------
    float l2 = 0.f;
#pragma unroll
    for (int j = 0; j < TPL; ++j) {
      float* rj; float s; int bi;
      if (j == 0)      { rj = r0; s = bestA; bi = idxA; }
      else if (j == 1) { rj = r1; s = bestB; bi = idxB; }
      else             { rj = r2; s = bestC; bi = idxC; }
      const float* __restrict__ eW =
          en + ((size_t)lvl * NCODE + bi) * D_ + h * 64;
#pragma unroll
      for (int d4 = 0; d4 < 16; ++d4) {
        float4 ev = *(const float4*)&eW[d4 * 4];
        float n0 = fmaf(-s, ev.x, rj[d4 * 4 + 0]);
        float n1 = fmaf(-s, ev.y, rj[d4 * 4 + 1]);
        float n2 = fmaf(-s, ev.z, rj[d4 * 4 + 2]);
        float n3 = fmaf(-s, ev.w, rj[d4 * 4 + 3]);
        rj[d4 * 4 + 0] = n0; rj[d4 * 4 + 1] = n1;
        rj[d4 * 4 + 2] = n2; rj[d4 * 4 + 3] = n3;
        l2 += n0 * n0 + n1 * n1 + n2 * n2 + n3 * n3;
      }
      size_t tok = base + (size_t)j * 32 + p;
      if (h == 0 && tok < NTOK) {
        out_idx[tok * 4 + lvl] = (float)bi;
        out_s[tok * 4 + lvl]   = s;
      }
    }

    // loss: 64-lane reduce (covers both halves, all 3 tokens), one atomic
#pragma unroll
    for (int m = 32; m >= 1; m >>= 1) l2 += __shfl_xor(l2, m);
    if (t == 0) atomicAdd(&lossacc_g[lvl], (double)l2);
  }

  // ---- stage-out: x_q = x - r_final ----------------------------------------
#pragma unroll
  for (int j = 0; j < TPL; ++j) {
    __syncthreads();
    const float* rj = (j == 0) ? r0 : (j == 1) ? r1 : r2;
#pragma unroll
    for (int d4 = 0; d4 < 16; ++d4) {
      float4 v;
      v.x = rj[d4 * 4 + 0]; v.y = rj[d4 * 4 + 1];
      v.z = rj[d4 * 4 + 2]; v.w = rj[d4 * 4 + 3];
      *(float4*)&sh[p * SSTR + h * 64 + d4 * 4] = v;
    }
    __syncthreads();
    const size_t tb = base + (size_t)j * 32;
#pragma unroll
    for (int it = 0; it < 16; ++it) {
      int g = it * 64 + t;
      size_t tok = tb + (size_t)(g >> 5);
      if (tok < NTOK) {
        float4 xv = *(const float4*)(x + tok * D_ + (size_t)(g & 31) * 4);
        float4 rv = *(const float4*)&sh[(g >> 5) * SSTR + ((g & 31) << 2)];
        float4 o;
        o.x = xv.x - rv.x; o.y = xv.y - rv.y;
        o.z = xv.z - rv.z; o.w = xv.w - rv.w;
        *(float4*)(out_xq + tok * D_ + (size_t)(g & 31) * 4) = o;
      }
    }
  }
}

// --- Kernel 3: finalize mean loss -------------------------------------------
// loss_l = (1+BETA) * S_l / (N*D);  mean over 4 levels
__global__ void finalize_loss(const double* __restrict__ lossacc_g,
                              float* __restrict__ out_loss) {
  double tot = lossacc_g[0] + lossacc_g[1] + lossacc_g[2] + lossacc_g[3];
  out_loss[0] = (float)(1.25 * tot / (4.0 * 16777216.0));
}

extern "C" void kernel_launch(void* const* d_in, const int* in_sizes, int n_in,
                              void* d_out, int out_size, void* d_ws, size_t ws_size,
                              hipStream_t stream) {
  const float* x  = (const float*)d_in[0];
  const float* cb = (const float*)d_in[1];

  float* out      = (float*)d_out;
  float* out_xq   = out;                                  // [N,128]
  float* out_loss = out + (size_t)NTOK * D_;              // [1]
  float* out_idx  = out_loss + 1;                         // [N,4] (as float)
  float* out_s    = out_idx + (size_t)NTOK * NLVL;        // [N,4]

  double* lossacc = (double*)d_ws;                        // 4 doubles
  float*  en      = (float*)((char*)d_ws + 256);          // normalized codebooks (512 KB)

  hipMemsetAsync(d_ws, 0, 256, stream);
  normalize_cb<<<NLVL * NCODE, 64, 0, stream>>>(cb, en);
  rvq_main<<<NBLK, 64, 0, stream>>>(x, en, out_xq, out_idx, out_s, lossacc);
  finalize_loss<<<1, 1, 0, stream>>>(lossacc, out_loss);

  (void)in_sizes; (void)n_in; (void)out_size; (void)ws_size;
}

// Round 8
// 994.114 us; speedup vs baseline: 1.1820x; 1.1820x over previous
//
#include <hip/hip_runtime.h>
#include <math.h>

#define EPSF 1e-8f

constexpr int D_    = 128;
constexpr int NTOK  = 131072;   // 1024 * 128
constexpr int NLVL  = 4;
constexpr int NCODE = 256;
constexpr int CHUNK = 32;       // codes staged in LDS per stage
constexpr int TOKB  = 96;       // tokens per block (1 wave: 16 slots x 6)
constexpr int NBLK  = (NTOK + TOKB - 1) / TOKB;   // 1366; last block has 32 real tokens
constexpr int ESTR  = 144;      // e-chunk row stride: 4 quarters x 36 floats (skewed banks)
constexpr int SSTR  = 132;      // token transpose stride

// --- Kernel 1: normalize codebook rows: e_n = e / (||e|| + eps) -------------
__global__ __launch_bounds__(64) void normalize_cb(const float* __restrict__ cb,
                                                   float* __restrict__ out) {
  int row = blockIdx.x;
  int t   = threadIdx.x;
  float a = cb[row * D_ + t];
  float b = cb[row * D_ + t + 64];
  float ss = a * a + b * b;
#pragma unroll
  for (int m = 32; m >= 1; m >>= 1) ss += __shfl_xor(ss, m);
  float denom = sqrtf(ss) + EPSF;
  out[row * D_ + t]      = a / denom;
  out[row * D_ + t + 64] = b / denom;
}

// --- Kernel 2: main RVQ ------------------------------------------------------
// 1 wave/block. lane = q*16 + p16: p16 = token slot (0..15), q = dim-quarter.
// Each slot owns 6 tokens (J=0..5): tok = blk*96 + J*16 + p16. Lane holds dims
// [32q, 32q+32) of each token in registers r0..r5[32] (static indices ONLY —
// no pointers to these arrays, they must stay in VGPRs).
// Per code: 8 broadcast ds_read_b128 feed 6x32 fmaf -> ~59 B LDS per wave-FMA,
// at/below the LDS return-bus budget. argmax of unnormalized r.e_n matches
// the reference's cosine argmax; the winning value IS the projection scalar.
__global__ __launch_bounds__(64, 2) void rvq_main(const float* __restrict__ x,
                                                  const float* __restrict__ en,
                                                  float* __restrict__ out_xq,
                                                  float* __restrict__ out_idx,
                                                  float* __restrict__ out_s,
                                                  double* __restrict__ lossacc_g) {
  __shared__ float sh[CHUNK * ESTR];   // 18 KB; also token transpose buf (16*132)

  const int t   = threadIdx.x;
  const int p16 = t & 15;
  const int q   = t >> 4;
  const size_t base = (size_t)blockIdx.x * TOKB;

  float r0[32], r1[32], r2[32], r3[32], r4[32], r5[32];

  // ---- stage-in: per J, 16 tokens coalesced -> LDS transpose -> registers --
#define STAGE_IN(RJ, JI)                                                      \
  {                                                                           \
    __syncthreads();                                                          \
    const size_t tb = base + (size_t)(JI) * 16;                               \
    _Pragma("unroll")                                                         \
    for (int it = 0; it < 8; ++it) {                                          \
      int g = it * 64 + t;                                                    \
      size_t tok = tb + (size_t)(g >> 5);                                     \
      float4 v = make_float4(0.f, 0.f, 0.f, 0.f);                             \
      if (tok < NTOK) v = *(const float4*)(x + tok * D_ + (size_t)(g & 31) * 4); \
      *(float4*)&sh[(g >> 5) * SSTR + ((g & 31) << 2)] = v;                   \
    }                                                                         \
    __syncthreads();                                                          \
    _Pragma("unroll")                                                         \
    for (int d4 = 0; d4 < 8; ++d4) {                                          \
      float4 v = *(const float4*)&sh[p16 * SSTR + q * 32 + d4 * 4];           \
      RJ[d4 * 4 + 0] = v.x; RJ[d4 * 4 + 1] = v.y;                             \
      RJ[d4 * 4 + 2] = v.z; RJ[d4 * 4 + 3] = v.w;                             \
    }                                                                         \
  }
  STAGE_IN(r0, 0) STAGE_IN(r1, 1) STAGE_IN(r2, 2)
  STAGE_IN(r3, 3) STAGE_IN(r4, 4) STAGE_IN(r5, 5)

  // ---- 4 residual levels ----
  for (int lvl = 0; lvl < NLVL; ++lvl) {
    float best0 = -3.0e38f, best1 = -3.0e38f, best2 = -3.0e38f;
    float best3 = -3.0e38f, best4 = -3.0e38f, best5 = -3.0e38f;
    int bidx0 = 0, bidx1 = 0, bidx2 = 0, bidx3 = 0, bidx4 = 0, bidx5 = 0;

    for (int ch = 0; ch < NCODE / CHUNK; ++ch) {
      __syncthreads();
      // stage 32 codes: global [code][128] -> LDS [code][quarter][36]
      const float4* __restrict__ eg =
          (const float4*)(en + ((size_t)lvl * NCODE + ch * CHUNK) * D_);
#pragma unroll
      for (int it = 0; it < 16; ++it) {
        int g = it * 64 + t;                 // 0..1023
        int code = g >> 5, within = g & 31;
        float4 v = eg[g];
        *(float4*)&sh[code * ESTR + (within >> 3) * 36 + (within & 7) * 4] = v;
      }
      __syncthreads();

      for (int code = 0; code < CHUNK; ++code) {
        const float* __restrict__ er = &sh[code * ESTR + q * 36];
        float sa0 = 0.f, sb0 = 0.f, sa1 = 0.f, sb1 = 0.f, sa2 = 0.f, sb2 = 0.f;
        float sa3 = 0.f, sb3 = 0.f, sa4 = 0.f, sb4 = 0.f, sa5 = 0.f, sb5 = 0.f;
#pragma unroll
        for (int kk = 0; kk < 4; ++kk) {
          float4 e0 = *(const float4*)&er[kk * 8];
          float4 e1 = *(const float4*)&er[kk * 8 + 4];
#define ACC8(J)                                                   \
          sa##J = fmaf(e0.x, r##J[kk * 8 + 0], sa##J);            \
          sa##J = fmaf(e0.y, r##J[kk * 8 + 1], sa##J);            \
          sa##J = fmaf(e0.z, r##J[kk * 8 + 2], sa##J);            \
          sa##J = fmaf(e0.w, r##J[kk * 8 + 3], sa##J);            \
          sb##J = fmaf(e1.x, r##J[kk * 8 + 4], sb##J);            \
          sb##J = fmaf(e1.y, r##J[kk * 8 + 5], sb##J);            \
          sb##J = fmaf(e1.z, r##J[kk * 8 + 6], sb##J);            \
          sb##J = fmaf(e1.w, r##J[kk * 8 + 7], sb##J);
          ACC8(0) ACC8(1) ACC8(2) ACC8(3) ACC8(4) ACC8(5)
        }
        int gc = ch * CHUNK + code;
#define ARGMAX(J)                                                 \
        {                                                         \
          float sv = sa##J + sb##J;                               \
          sv += __shfl_xor(sv, 16);                               \
          sv += __shfl_xor(sv, 32);                               \
          if (sv > best##J) { best##J = sv; bidx##J = gc; }       \
        }
        ARGMAX(0) ARGMAX(1) ARGMAX(2) ARGMAX(3) ARGMAX(4) ARGMAX(5)
      }
    }

    // ---- update: gather winner rows from L2; r -= s*e; loss ----------------
    float l2 = 0.f;
#define UPDATE(RJ, J, JI)                                                     \
    {                                                                         \
      float s = best##J; int bi = bidx##J;                                    \
      const float* __restrict__ ew =                                          \
          en + ((size_t)lvl * NCODE + bi) * D_ + q * 32;                      \
      _Pragma("unroll")                                                       \
      for (int d4 = 0; d4 < 8; ++d4) {                                        \
        float4 ev = *(const float4*)&ew[d4 * 4];                              \
        float n0 = fmaf(-s, ev.x, RJ[d4 * 4 + 0]);                            \
        float n1 = fmaf(-s, ev.y, RJ[d4 * 4 + 1]);                            \
        float n2 = fmaf(-s, ev.z, RJ[d4 * 4 + 2]);                            \
        float n3 = fmaf(-s, ev.w, RJ[d4 * 4 + 3]);                            \
        RJ[d4 * 4 + 0] = n0; RJ[d4 * 4 + 1] = n1;                             \
        RJ[d4 * 4 + 2] = n2; RJ[d4 * 4 + 3] = n3;                             \
        l2 += n0 * n0 + n1 * n1 + n2 * n2 + n3 * n3;                          \
      }                                                                       \
      size_t tok = base + (size_t)(JI) * 16 + p16;                            \
      if (q == 0 && tok < NTOK) {                                             \
        out_idx[tok * 4 + lvl] = (float)bi;                                   \
        out_s[tok * 4 + lvl]   = s;                                           \
      }                                                                       \
    }
    UPDATE(r0, 0, 0) UPDATE(r1, 1, 1) UPDATE(r2, 2, 2)
    UPDATE(r3, 3, 3) UPDATE(r4, 4, 4) UPDATE(r5, 5, 5)

    // loss: 64-lane reduce covers all quarters & slots; one atomic per wave
#pragma unroll
    for (int m = 32; m >= 1; m >>= 1) l2 += __shfl_xor(l2, m);
    if (t == 0) atomicAdd(&lossacc_g[lvl], (double)l2);
  }

  // ---- stage-out: x_q = x - r_final ----------------------------------------
#define STAGE_OUT(RJ, JI)                                                     \
  {                                                                           \
    __syncthreads();                                                          \
    _Pragma("unroll")                                                         \
    for (int d4 = 0; d4 < 8; ++d4) {                                          \
      float4 v;                                                               \
      v.x = RJ[d4 * 4 + 0]; v.y = RJ[d4 * 4 + 1];                             \
      v.z = RJ[d4 * 4 + 2]; v.w = RJ[d4 * 4 + 3];                             \
      *(float4*)&sh[p16 * SSTR + q * 32 + d4 * 4] = v;                        \
    }                                                                         \
    __syncthreads();                                                          \
    const size_t tb = base + (size_t)(JI) * 16;                               \
    _Pragma("unroll")                                                         \
    for (int it = 0; it < 8; ++it) {                                          \
      int g = it * 64 + t;                                                    \
      size_t tok = tb + (size_t)(g >> 5);                                     \
      if (tok < NTOK) {                                                       \
        float4 xv = *(const float4*)(x + tok * D_ + (size_t)(g & 31) * 4);    \
        float4 rv = *(const float4*)&sh[(g >> 5) * SSTR + ((g & 31) << 2)];   \
        float4 o;                                                             \
        o.x = xv.x - rv.x; o.y = xv.y - rv.y;                                 \
        o.z = xv.z - rv.z; o.w = xv.w - rv.w;                                 \
        *(float4*)(out_xq + tok * D_ + (size_t)(g & 31) * 4) = o;             \
      }                                                                       \
    }                                                                         \
  }
  STAGE_OUT(r0, 0) STAGE_OUT(r1, 1) STAGE_OUT(r2, 2)
  STAGE_OUT(r3, 3) STAGE_OUT(r4, 4) STAGE_OUT(r5, 5)
}

// --- Kernel 3: finalize mean loss -------------------------------------------
__global__ void finalize_loss(const double* __restrict__ lossacc_g,
                              float* __restrict__ out_loss) {
  double tot = lossacc_g[0] + lossacc_g[1] + lossacc_g[2] + lossacc_g[3];
  out_loss[0] = (float)(1.25 * tot / (4.0 * 16777216.0));
}

extern "C" void kernel_launch(void* const* d_in, const int* in_sizes, int n_in,
                              void* d_out, int out_size, void* d_ws, size_t ws_size,
                              hipStream_t stream) {
  const float* x  = (const float*)d_in[0];
  const float* cb = (const float*)d_in[1];

  float* out      = (float*)d_out;
  float* out_xq   = out;                                  // [N,128]
  float* out_loss = out + (size_t)NTOK * D_;              // [1]
  float* out_idx  = out_loss + 1;                         // [N,4] (as float)
  float* out_s    = out_idx + (size_t)NTOK * NLVL;        // [N,4]

  double* lossacc = (double*)d_ws;                        // 4 doubles
  float*  en      = (float*)((char*)d_ws + 256);          // normalized codebooks (512 KB)

  hipMemsetAsync(d_ws, 0, 256, stream);
  normalize_cb<<<NLVL * NCODE, 64, 0, stream>>>(cb, en);
  rvq_main<<<NBLK, 64, 0, stream>>>(x, en, out_xq, out_idx, out_s, lossacc);
  finalize_loss<<<1, 1, 0, stream>>>(lossacc, out_loss);

  (void)in_sizes; (void)n_in; (void)out_size; (void)ws_size;
}